// Round 1
// baseline (33.556 us; speedup 1.0000x reference)
//
#include <hip/hip_runtime.h>

#define B_ 2
#define N_ 28
#define D_ 128
#define H_ 8
#define DK_ 16
#define R_ (B_ * N_ * N_)   // 1568 rows of the flattened (b,n1,n2) axis
#define ROWS_PER_BLK 8      // 1568 / 8 = 196 blocks exactly

// ---------------------------------------------------------------------------
// Kernel 1: all four projections  Y_p = X_p @ W_p^T
//   p = 0: lk = key  @ Wlk^T
//   p = 1: rk = key  @ Wrk^T
//   p = 2: lv = value@ Wlv^T
//   p = 3: rv = value@ Wrv^T
// Output layout in ws: [p][R_][128] floats.
// ---------------------------------------------------------------------------
__global__ __launch_bounds__(128) void proj4_kernel(
    const float* __restrict__ key, const float* __restrict__ value,
    const float* __restrict__ Wlk, const float* __restrict__ Wrk,
    const float* __restrict__ Wlv, const float* __restrict__ Wrv,
    float* __restrict__ ws) {
  const int p = blockIdx.y;
  const float* X = (p < 2) ? key : value;
  const float* W = (p == 0) ? Wlk : (p == 1) ? Wrk : (p == 2) ? Wlv : Wrv;
  float* Y = ws + (size_t)p * R_ * D_;

  const int r0 = blockIdx.x * ROWS_PER_BLK;
  const int c = threadIdx.x;  // output column 0..127

  __shared__ float xs[ROWS_PER_BLK][D_];
#pragma unroll
  for (int i = 0; i < ROWS_PER_BLK; ++i)
    xs[i][c] = X[(size_t)(r0 + i) * D_ + c];
  __syncthreads();

  const float4* w4 = reinterpret_cast<const float4*>(W + (size_t)c * D_);
  float acc[ROWS_PER_BLK];
#pragma unroll
  for (int i = 0; i < ROWS_PER_BLK; ++i) acc[i] = 0.f;

#pragma unroll
  for (int k = 0; k < D_ / 4; ++k) {
    const float4 wv = w4[k];
#pragma unroll
    for (int i = 0; i < ROWS_PER_BLK; ++i) {
      const float4 xv = reinterpret_cast<const float4*>(xs[i])[k];
      acc[i] += xv.x * wv.x + xv.y * wv.y + xv.z * wv.z + xv.w * wv.w;
    }
  }

#pragma unroll
  for (int i = 0; i < ROWS_PER_BLK; ++i)
    Y[(size_t)(r0 + i) * D_ + c] = acc[i];
}

// ---------------------------------------------------------------------------
// Kernel 2: per (b,x,y) block: scores over a (dot over d via shfl), mask,
// softmax over a, then x[h,d] = sum_a att[a]*lv*rv. Writes pre-Wout x to ws.
// 128 threads = (h = tid>>4, d = tid&15).
// ---------------------------------------------------------------------------
__global__ __launch_bounds__(128) void attn_kernel(
    const float* __restrict__ ws, const int* __restrict__ mask,
    float* __restrict__ xout) {
  const float* lk = ws;
  const float* rk = ws + (size_t)1 * R_ * D_;
  const float* lv = ws + (size_t)2 * R_ * D_;
  const float* rv = ws + (size_t)3 * R_ * D_;

  const int bxy = blockIdx.x;   // 0..1567  == (b*28 + x)*28 + y
  const int y = bxy % N_;
  const int bx = bxy / N_;      // b*28 + x
  const int b = bx / N_;
  const int tid = threadIdx.x;  // == h*16 + d

  const int rowL = bx * N_;            // + a          (rows of lk / lv)
  const int rowR = b * N_ * N_ + y;    // + a*N_       (rows of rk / rv)

  float s[N_];
#pragma unroll
  for (int a = 0; a < N_; ++a) {
    float pr = lk[(size_t)(rowL + a) * D_ + tid] *
               rk[(size_t)(rowR + a * N_) * D_ + tid];
    // reduce over the 16 lanes of this head (lanes are 16-aligned groups)
    pr += __shfl_xor(pr, 1);
    pr += __shfl_xor(pr, 2);
    pr += __shfl_xor(pr, 4);
    pr += __shfl_xor(pr, 8);
    s[a] = pr * 0.25f;  // / sqrt(DK) = / 4
  }

  const int* mrow = mask + (size_t)rowL * N_ + y;  // mask[(rowL+a)*28 + y]
#pragma unroll
  for (int a = 0; a < N_; ++a)
    if (mrow[(size_t)a * N_] != 0) s[a] = -1e9f;

  float mx = -3.0e38f;
#pragma unroll
  for (int a = 0; a < N_; ++a) mx = fmaxf(mx, s[a]);
  float den = 0.f;
#pragma unroll
  for (int a = 0; a < N_; ++a) {
    s[a] = __expf(s[a] - mx);
    den += s[a];
  }
  const float inv = 1.0f / den;

  float xv = 0.f;
#pragma unroll
  for (int a = 0; a < N_; ++a) {
    xv += s[a] * lv[(size_t)(rowL + a) * D_ + tid] *
          rv[(size_t)(rowR + a * N_) * D_ + tid];
  }
  xout[(size_t)bxy * D_ + tid] = xv * inv;
}

// ---------------------------------------------------------------------------
// Kernel 3: out = x @ Wout^T   ([1568,128] x [128,128])
// ---------------------------------------------------------------------------
__global__ __launch_bounds__(128) void gemm_out_kernel(
    const float* __restrict__ X, const float* __restrict__ W,
    float* __restrict__ Y) {
  const int r0 = blockIdx.x * ROWS_PER_BLK;
  const int c = threadIdx.x;

  __shared__ float xs[ROWS_PER_BLK][D_];
#pragma unroll
  for (int i = 0; i < ROWS_PER_BLK; ++i)
    xs[i][c] = X[(size_t)(r0 + i) * D_ + c];
  __syncthreads();

  const float4* w4 = reinterpret_cast<const float4*>(W + (size_t)c * D_);
  float acc[ROWS_PER_BLK];
#pragma unroll
  for (int i = 0; i < ROWS_PER_BLK; ++i) acc[i] = 0.f;

#pragma unroll
  for (int k = 0; k < D_ / 4; ++k) {
    const float4 wv = w4[k];
#pragma unroll
    for (int i = 0; i < ROWS_PER_BLK; ++i) {
      const float4 xv = reinterpret_cast<const float4*>(xs[i])[k];
      acc[i] += xv.x * wv.x + xv.y * wv.y + xv.z * wv.z + xv.w * wv.w;
    }
  }

#pragma unroll
  for (int i = 0; i < ROWS_PER_BLK; ++i)
    Y[(size_t)(r0 + i) * D_ + c] = acc[i];
}

extern "C" void kernel_launch(void* const* d_in, const int* in_sizes, int n_in,
                              void* d_out, int out_size, void* d_ws,
                              size_t ws_size, hipStream_t stream) {
  // setup_inputs order:
  // 0 query (unused), 1 key, 2 value, 3 mask, 4 Wlk, 5 Wrk, 6 Wlv, 7 Wrv,
  // 8 Wq (unused), 9 Wout
  const float* key = (const float*)d_in[1];
  const float* value = (const float*)d_in[2];
  const int* mask = (const int*)d_in[3];
  const float* Wlk = (const float*)d_in[4];
  const float* Wrk = (const float*)d_in[5];
  const float* Wlv = (const float*)d_in[6];
  const float* Wrv = (const float*)d_in[7];
  const float* Wout = (const float*)d_in[9];
  float* out = (float*)d_out;

  float* ws = (float*)d_ws;
  float* xbuf = ws + (size_t)4 * R_ * D_;  // pre-Wout x, [1568][128]

  proj4_kernel<<<dim3(R_ / ROWS_PER_BLK, 4), 128, 0, stream>>>(
      key, value, Wlk, Wrk, Wlv, Wrv, ws);
  attn_kernel<<<dim3(R_), 128, 0, stream>>>(ws, mask, xbuf);
  gemm_out_kernel<<<dim3(R_ / ROWS_PER_BLK), 128, 0, stream>>>(xbuf, Wout, out);
}